// Round 9
// baseline (6249.758 us; speedup 1.0000x reference)
//
#include <hip/hip_runtime.h>

#define B_ 256
#define S_ 256
#define D_ 64
#define H_ 1024
#define G4 4096
#define TOUT 32

typedef unsigned short u16;
typedef __attribute__((ext_vector_type(8))) short short8;
typedef __attribute__((ext_vector_type(4))) float float4v;
typedef __attribute__((ext_vector_type(16))) float f32x16;

__device__ __forceinline__ float bf2f(u16 b) {
  return __uint_as_float(((unsigned int)b) << 16);
}
__device__ __forceinline__ u16 f2bf(float f) {
  unsigned int u = __float_as_uint(f);
  unsigned int r = (u + 0x7fffu + ((u >> 16) & 1u)) >> 16;
  return (u16)r;
}
__device__ __forceinline__ unsigned pack2(float a, float b) {
  return (unsigned)f2bf(a) | ((unsigned)f2bf(b) << 16);
}
__device__ __forceinline__ float sigm(float x) {
  return 1.f / (1.f + __expf(-x));
}
__device__ __forceinline__ float tanh_(float x) {
  float xc = fminf(fmaxf(x, -15.f), 15.f);
  float e = __expf(2.f * xc);
  return (e - 1.f) / (e + 1.f);
}

__global__ __launch_bounds__(256) void cvt_kernel(const float* __restrict__ src,
                                                  u16* __restrict__ dst, int n) {
  for (int i = blockIdx.x * blockDim.x + threadIdx.x; i < n;
       i += gridDim.x * blockDim.x)
    dst[i] = f2bf(src[i]);
}

__global__ __launch_bounds__(256) void zero_kernel(uint4* __restrict__ p, int n16) {
  for (int i = blockIdx.x * blockDim.x + threadIdx.x; i < n16;
       i += gridDim.x * blockDim.x)
    p[i] = make_uint4(0u, 0u, 0u, 0u);
}

struct LayerDesc {
  const u16* A0; int lda0;
  const u16* A1; int lda1; int klen0;
  const void* W0; int ldw0;
  const void* W1; int ldw1; int Ktot;
  const float* bias;   // fp32 [4096] original gate-blocked
  const float* wcol;   // fp32 [4096] dec input column, or null
  const float* inp;    // fp32 [B] scalar input, or null
  float* c;
  u16* h;
  int active;
  // extensions (all null for legacy uses):
  float* gout;         // if set: write raw gates [B][H][4] and skip the cell
  const float* fcW;    // with pred: fused fc weights (fp32 [H])
  float* pred;         // fused fc accumulator [B] (atomicAdd), pre-zeroed
};

// Paired LSTM step: blockIdx.y<4 -> dA (slot A), >=4 -> dB (slot B).
// Each 64x64 tile: gates = [A0|A1] @ [W0|W1]^T (+bias +inp*wcol in cell mode).
//
// v9 = v8 (K-split 32x32x16 core, cooperative reg-staged LDS dbuf, one barrier
// per 64-k chunk) + REGISTER PREFETCH ACROSS THE BARRIER:
//   fragments of chunk kc+1 are ds_read at the START of iteration kc (buffer
//   published by the previous barrier); MFMAs of chunk kc consume registers
//   read a full iteration earlier -> the ds_read->MFMA latency (~150-250 cyc,
//   the measured residual after v8's null LDS-count result) is fully hidden.
//   Prologue stages chunks 0+1 into both buffers; iter kc stages chunk kc+2
//   into buf[kc&1] (its last readers were fenced by the previous barrier);
//   barrier only when a stage occurred.  Same 2 buffers, <=1 barrier/chunk.
template <bool WF32>
__global__ __launch_bounds__(256) void lstm_step_kernel(LayerDesc dA, LayerDesc dB)
{
  const bool second = (blockIdx.y >= 4);
  const LayerDesc d = second ? dB : dA;
  if (!d.active) return;

  // [0,18432) As[2][64][72], [18432,36864) Bs[2][64][72], [36864,54272) Gs[64][68]
  // epilogue scratch: 12 x 4096B regions at [0,49152) (staging dead; regions
  // 9-11 overlap Gs head -> extra barrier before the Gs scatter)
  __shared__ __align__(16) unsigned char SMEM[54272];
  u16 (*As)[64][72] = (u16(*)[64][72])(SMEM);
  u16 (*Bs)[64][72] = (u16(*)[64][72])(SMEM + 18432);
  float* Gs = (float*)(SMEM + 36864);   // row stride 68 floats
  float* scr = (float*)SMEM;            // 12 x 1024-float regions

  const int tid = threadIdx.x;
  const int m0 = (second ? (blockIdx.y - 4) : blockIdx.y) * 64;
  const int n0 = blockIdx.x * 64;
  const int ub = n0 >> 2;        // first hidden unit of this block
  const int r = tid >> 2;        // staging row 0..63
  const int q = tid & 3;         // staging 16-col group
  const int lane = tid & 63;
  const int wv = tid >> 6;
  const int l31 = lane & 31;

  const int klen0 = d.klen0;
  const u16* aw0 = d.A0 + (size_t)(m0 + r) * d.lda0;
  const u16* aw1 = d.A1 + (size_t)(m0 + r) * d.lda1;
  const int orow = (r & 3) * H_ + ub + (r >> 2);  // gate-col n0+r -> original W row
  const u16* bw0_h = (const u16*)d.W0 + (size_t)orow * d.ldw0;
  const u16* bw1_h = (const u16*)d.W1 + (size_t)orow * d.ldw1;
  const float* bw0_f = (const float*)d.W0 + (size_t)orow * d.ldw0;
  const float* bw1_f = (const float*)d.W1 + (size_t)orow * d.ldw1;

  uint4 av0, av1, bv0, bv1;
  float4 bf0, bf1, bf2, bf3;

  auto load_chunk = [&](int kc) {   // global -> regs (v4/v8 path, unchanged)
    const int kg = kc * 64 + q * 16;
    const bool first = kg < klen0;
    const u16* pa = first ? (aw0 + kg) : (aw1 + (kg - klen0));
    av0 = *(const uint4*)pa;
    av1 = *(const uint4*)(pa + 8);
    if constexpr (WF32) {
      const float* pb = first ? (bw0_f + kg) : (bw1_f + (kg - klen0));
      bf0 = *(const float4*)pb;
      bf1 = *(const float4*)(pb + 4);
      bf2 = *(const float4*)(pb + 8);
      bf3 = *(const float4*)(pb + 12);
    } else {
      const u16* pb = first ? (bw0_h + kg) : (bw1_h + (kg - klen0));
      bv0 = *(const uint4*)pb;
      bv1 = *(const uint4*)(pb + 8);
    }
  };

  auto stage = [&](int buf) {  // regs -> LDS (vmcnt auto-gated by compiler)
    if constexpr (WF32) {
      bv0 = make_uint4(pack2(bf0.x, bf0.y), pack2(bf0.z, bf0.w),
                       pack2(bf1.x, bf1.y), pack2(bf1.z, bf1.w));
      bv1 = make_uint4(pack2(bf2.x, bf2.y), pack2(bf2.z, bf2.w),
                       pack2(bf3.x, bf3.y), pack2(bf3.z, bf3.w));
    }
    *(uint4*)&As[buf][r][q * 16]     = av0;
    *(uint4*)&As[buf][r][q * 16 + 8] = av1;
    *(uint4*)&Bs[buf][r][q * 16]     = bv0;
    *(uint4*)&Bs[buf][r][q * 16 + 8] = bv1;
  };

  f32x16 acc00 = {}, acc01 = {}, acc10 = {}, acc11 = {};
  const int kb = wv * 16 + (lane >> 5) * 8;   // this wave's k-window + frag k
  const int nch = d.Ktot >> 6;

  auto readF = [&](int buf, short8* f) {      // LDS -> fragment regs
    f[0] = *(const short8*)&As[buf][l31][kb];
    f[1] = *(const short8*)&As[buf][l31 + 32][kb];
    f[2] = *(const short8*)&Bs[buf][l31][kb];
    f[3] = *(const short8*)&Bs[buf][l31 + 32][kb];
  };

  // prologue: stage chunks 0 and 1 into both buffers; issue load 2
  load_chunk(0);
  stage(0);
  if (nch > 1) { load_chunk(1); stage(1); }
  if (nch > 2) load_chunk(2);
  __syncthreads();  // buf0 + buf1 ready

  short8 rC[4], rN[4];
  readF(0, rC);     // chunk 0 fragments

  for (int kc = 0; kc < nch; ++kc) {
    if (kc + 1 < nch) readF((kc + 1) & 1, rN);   // prefetch next chunk's frags
    acc00 = __builtin_amdgcn_mfma_f32_32x32x16_bf16(rC[0], rC[2], acc00, 0, 0, 0);
    acc01 = __builtin_amdgcn_mfma_f32_32x32x16_bf16(rC[0], rC[3], acc01, 0, 0, 0);
    acc10 = __builtin_amdgcn_mfma_f32_32x32x16_bf16(rC[1], rC[2], acc10, 0, 0, 0);
    acc11 = __builtin_amdgcn_mfma_f32_32x32x16_bf16(rC[1], rC[3], acc11, 0, 0, 0);
    if (kc + 2 < nch) {
      stage(kc & 1);                        // chunk kc+2 (readers fenced by prev barrier)
      if (kc + 3 < nch) load_chunk(kc + 3); // ~1+ iteration of lead
      __syncthreads();                      // publish buf[kc&1]; fence this iter's reads
    }
    if (kc + 1 < nch) {
      rC[0] = rN[0]; rC[1] = rN[1]; rC[2] = rN[2]; rC[3] = rN[3];
    }
  }

  // ---- cross-wave K-reduction (v6/v8-proven): wave wv owns quadrant
  // (rows (wv>>1)*32, cols (wv&1)*32); acc order 00,01,10,11 = quadrants 0..3
  __syncthreads();   // all staging reads done; reuse As/Bs (+Gs head) as scratch

  auto store_frag = [&](const f32x16& A, int qd) {
    if (qd == wv) return;
    const int slot = (wv > qd) ? (wv - 1) : wv;
    float* rg = scr + (qd * 3 + slot) * 1024 + lane * 4;
#pragma unroll
    for (int j4 = 0; j4 < 4; ++j4)
      *(float4*)&rg[j4 * 256] = make_float4(A[j4 * 4 + 0], A[j4 * 4 + 1],
                                            A[j4 * 4 + 2], A[j4 * 4 + 3]);
  };
  store_frag(acc00, 0);
  store_frag(acc01, 1);
  store_frag(acc10, 2);
  store_frag(acc11, 3);
  __syncthreads();

  f32x16 fin = (wv == 0) ? acc00 : (wv == 1) ? acc01 : (wv == 2) ? acc10 : acc11;
#pragma unroll
  for (int s = 0; s < 3; ++s) {
    const float* rg = scr + (wv * 3 + s) * 1024 + lane * 4;
#pragma unroll
    for (int j4 = 0; j4 < 4; ++j4) {
      const float4 v = *(const float4*)&rg[j4 * 256];
      fin[j4 * 4 + 0] += v.x;
      fin[j4 * 4 + 1] += v.y;
      fin[j4 * 4 + 2] += v.z;
      fin[j4 * 4 + 3] += v.w;
    }
  }
  __syncthreads();   // regions 9-11 consumed before Gs scatter overwrites them

  // scatter owned quadrant to Gs; 32x32 C-layout: col=lane&31,
  // row=(reg&3)+8*(reg>>2)+4*(lane>>5)   [verified in v6/m101]
  {
    const int rbase = (wv >> 1) * 32 + (lane >> 5) * 4;
    const int col = (wv & 1) * 32 + l31;
#pragma unroll
    for (int j = 0; j < 16; ++j) {
      const int row = rbase + (j & 3) + 8 * (j >> 2);
      Gs[row * 68 + col] = fin[j];
    }
  }
  __syncthreads();

  if (d.gout != nullptr) {
    // raw-gates mode: gout[bg][J][g] = Gs[bl][u*4+g]; bias/pred applied later
#pragma unroll
    for (int it = 0; it < 4; ++it) {
      const int p = tid + it * 256;
      const int bl = p >> 4;
      const int u = p & 15;
      const int J = ub + u;
      const int bg = m0 + bl;
      const float4v g = *(const float4v*)&Gs[bl * 68 + u * 4];
      *(float4*)&d.gout[((size_t)bg * H_ + J) * 4] =
          make_float4(g[0], g[1], g[2], g[3]);
    }
    return;
  }

  // fused LSTM cell: 64 batches x 16 units; local col 4u+g = gate g of unit ub+u
#pragma unroll
  for (int it = 0; it < 4; ++it) {
    const int p = tid + it * 256;
    const int bl = p >> 4;
    const int u = p & 15;          // == lane & 15
    const int J = ub + u;
    const int bg = m0 + bl;
    const float4v g = *(const float4v*)&Gs[bl * 68 + u * 4];
    float pi = g[0] + d.bias[J];
    float pf = g[1] + d.bias[H_ + J];
    float pg = g[2] + d.bias[2 * H_ + J];
    float po = g[3] + d.bias[3 * H_ + J];
    if (d.inp != nullptr) {
      const float iv = d.inp[bg];
      pi += iv * d.wcol[J];
      pf += iv * d.wcol[H_ + J];
      pg += iv * d.wcol[2 * H_ + J];
      po += iv * d.wcol[3 * H_ + J];
    }
    const size_t idx = (size_t)bg * H_ + J;
    const float c = d.c[idx];
    const float cn = sigm(pf) * c + sigm(pi) * tanh_(pg);
    d.c[idx] = cn;
    const float hv = sigm(po) * tanh_(cn);
    d.h[idx] = f2bf(hv);
    if (d.pred != nullptr) {
      float s = hv * d.fcW[J];
      s += __shfl_xor(s, 1, 64);
      s += __shfl_xor(s, 2, 64);
      s += __shfl_xor(s, 4, 64);
      s += __shfl_xor(s, 8, 64);
      if (u == 0) atomicAdd(&d.pred[bg], s);   // 16-unit slice partial
    }
  }
}

// decoder layer0 cell: gates from GBUF (raw GEMM) + bias + iv*wcol, iv =
// pred_prev[b] + fcb (or 0 at t=0).  One block per batch, 4 units/thread.
__global__ __launch_bounds__(256) void dec_cell_kernel(
    const float* __restrict__ GBUF, const float* __restrict__ bias,
    const float* __restrict__ wcol, const float* __restrict__ pred_prev,
    const float* __restrict__ fcb, float* __restrict__ C,
    u16* __restrict__ hout)
{
  const int b = blockIdx.x;
  const int tid = threadIdx.x;
  const float iv = (pred_prev != nullptr) ? (pred_prev[b] + fcb[0]) : 0.f;
#pragma unroll
  for (int k = 0; k < 4; ++k) {
    const int J = tid + k * 256;
    const float4 g = *(const float4*)&GBUF[((size_t)b * H_ + J) * 4];
    const float pi = g.x + bias[J]          + iv * wcol[J];
    const float pf = g.y + bias[H_ + J]     + iv * wcol[H_ + J];
    const float pg = g.z + bias[2 * H_ + J] + iv * wcol[2 * H_ + J];
    const float po = g.w + bias[3 * H_ + J] + iv * wcol[3 * H_ + J];
    const size_t idx = (size_t)b * H_ + J;
    const float c0 = C[idx];
    const float cn = sigm(pf) * c0 + sigm(pi) * tanh_(pg);
    C[idx] = cn;
    hout[idx] = f2bf(sigm(po) * tanh_(cn));
  }
}

// out[b][t] = PRED[t][b] + fcb
__global__ __launch_bounds__(256) void dec_out_kernel(
    const float* __restrict__ PRED, const float* __restrict__ fcb,
    float* __restrict__ out)
{
  const int gid = blockIdx.x * 256 + threadIdx.x;
  const int b = gid >> 5;
  const int t = gid & 31;
  out[gid] = PRED[t * B_ + b] + fcb[0];
}

// pred[b] = fc_W . h1[b] + fc_b ; fp32 out + fp32 feedback (fallback path)
__global__ __launch_bounds__(256) void fc_kernel(
    const u16* __restrict__ h1, const float* __restrict__ fcW,
    const float* __restrict__ fcb, float* __restrict__ out,
    float* __restrict__ inp, int t)
{
  const int b = blockIdx.x;
  const int tid = threadIdx.x;
  const u16* hr = h1 + (size_t)b * H_ + tid * 4;
  const float* wr = fcW + tid * 4;
  float s = 0.f;
#pragma unroll
  for (int j = 0; j < 4; ++j) s += bf2f(hr[j]) * wr[j];
#pragma unroll
  for (int off = 32; off > 0; off >>= 1) s += __shfl_down(s, off, 64);
  __shared__ float red[4];
  if ((tid & 63) == 0) red[tid >> 6] = s;
  __syncthreads();
  if (tid == 0) {
    const float p = red[0] + red[1] + red[2] + red[3] + fcb[0];
    out[(size_t)b * TOUT + t] = p;
    inp[b] = p;
  }
}

extern "C" void kernel_launch(void* const* d_in, const int* in_sizes, int n_in,
                              void* d_out, int out_size, void* d_ws, size_t ws_size,
                              hipStream_t stream)
{
  const float* X     = (const float*)d_in[0];
  const float* eWih0 = (const float*)d_in[1];
  const float* eWhh0 = (const float*)d_in[2];
  const float* eb0   = (const float*)d_in[3];
  const float* eWih1 = (const float*)d_in[4];
  const float* eWhh1 = (const float*)d_in[5];
  const float* eb1   = (const float*)d_in[6];
  const float* dWih0 = (const float*)d_in[7];
  const float* dWhh0 = (const float*)d_in[8];
  const float* db0   = (const float*)d_in[9];
  const float* dWih1 = (const float*)d_in[10];
  const float* dWhh1 = (const float*)d_in[11];
  const float* db1   = (const float*)d_in[12];
  const float* fcW   = (const float*)d_in[13];
  const float* fcb   = (const float*)d_in[14];
  float* out = (float*)d_out;

  char* ws = (char*)d_ws;
  size_t off = 0;
  auto alloc = [&](size_t bytes) -> void* {
    void* p = ws + off;
    off += (bytes + 255) & ~(size_t)255;
    return p;
  };
  // state block first (zeroed every call)
  u16* h0buf[2], *h1buf[2];
  h0buf[0] = (u16*)alloc((size_t)B_ * H_ * 2);
  h0buf[1] = (u16*)alloc((size_t)B_ * H_ * 2);
  h1buf[0] = (u16*)alloc((size_t)B_ * H_ * 2);
  h1buf[1] = (u16*)alloc((size_t)B_ * H_ * 2);
  float* C0   = (float*)alloc((size_t)B_ * H_ * 4);
  float* C1   = (float*)alloc((size_t)B_ * H_ * 4);
  float* INP  = (float*)alloc(B_ * 4);
  float* PRED = (float*)alloc((size_t)TOUT * B_ * 4);  // zeroed (fc atomics)
  const size_t zbytes = off;
  u16* XB = (u16*)alloc((size_t)B_ * S_ * D_ * 2);
  // bf16 weight copies (fast path), original flat layouts
  u16* WB_eWih0 = (u16*)alloc((size_t)G4 * D_ * 2);
  u16* WB_eWhh0 = (u16*)alloc((size_t)G4 * H_ * 2);
  u16* WB_eWih1 = (u16*)alloc((size_t)G4 * H_ * 2);
  u16* WB_eWhh1 = (u16*)alloc((size_t)G4 * H_ * 2);
  u16* WB_dWhh0 = (u16*)alloc((size_t)G4 * H_ * 2);
  u16* WB_dWih1 = (u16*)alloc((size_t)G4 * H_ * 2);
  u16* WB_dWhh1 = (u16*)alloc((size_t)G4 * H_ * 2);
  float* GBUF   = (float*)alloc((size_t)B_ * H_ * 4 * 4);  // raw gates [B][H][4]
  const size_t need_full = off;
  const bool fast = (ws_size >= need_full);

  zero_kernel<<<dim3(256), dim3(256), 0, stream>>>((uint4*)ws, (int)(zbytes / 16));
  cvt_kernel<<<dim3(1024), dim3(256), 0, stream>>>(X, XB, B_ * S_ * D_);
  if (fast) {
    cvt_kernel<<<dim3(256), dim3(256), 0, stream>>>(eWih0, WB_eWih0, G4 * D_);
    cvt_kernel<<<dim3(1024), dim3(256), 0, stream>>>(eWhh0, WB_eWhh0, G4 * H_);
    cvt_kernel<<<dim3(1024), dim3(256), 0, stream>>>(eWih1, WB_eWih1, G4 * H_);
    cvt_kernel<<<dim3(1024), dim3(256), 0, stream>>>(eWhh1, WB_eWhh1, G4 * H_);
    cvt_kernel<<<dim3(1024), dim3(256), 0, stream>>>(dWhh0, WB_dWhh0, G4 * H_);
    cvt_kernel<<<dim3(1024), dim3(256), 0, stream>>>(dWih1, WB_dWih1, G4 * H_);
    cvt_kernel<<<dim3(1024), dim3(256), 0, stream>>>(dWhh1, WB_dWhh1, G4 * H_);
  }

  auto mk = [&](const u16* A0, int lda0, const u16* A1, int lda1, int klen0,
                const void* W0b, const void* W0f, int ldw0,
                const void* W1b, const void* W1f, int ldw1, int Ktot,
                const float* bias, const float* wcol, const float* inp,
                float* c, u16* h) {
    LayerDesc d;
    d.A0 = A0; d.lda0 = lda0; d.A1 = A1; d.lda1 = lda1; d.klen0 = klen0;
    d.W0 = fast ? W0b : W0f; d.ldw0 = ldw0;
    d.W1 = fast ? W1b : W1f; d.ldw1 = ldw1; d.Ktot = Ktot;
    d.bias = bias; d.wcol = wcol; d.inp = inp; d.c = c; d.h = h;
    d.active = 1;
    d.gout = nullptr; d.fcW = nullptr; d.pred = nullptr;
    return d;
  };
  LayerDesc off_d = {};
  off_d.active = 0;

  auto launch = [&](dim3 grid, const LayerDesc& a, const LayerDesc& b) {
    if (fast)
      lstm_step_kernel<false><<<grid, dim3(256), 0, stream>>>(a, b);
    else
      lstm_step_kernel<true><<<grid, dim3(256), 0, stream>>>(a, b);
  };

  // encoder, layer-pipelined: tick u runs L0(t=u) and L1(t=u-1) concurrently.
  // h ping-pong: L(t) reads hbuf[t&1], writes hbuf[(t+1)&1].
  for (int u = 0; u <= S_; ++u) {
    LayerDesc d0 = off_d, d1 = off_d;
    if (u < S_) {
      const int t = u;
      d0 = mk(XB + t * D_, S_ * D_, h0buf[t & 1], H_, D_,
              WB_eWih0, eWih0, D_, WB_eWhh0, eWhh0, H_, 1088,
              eb0, nullptr, nullptr, C0, h0buf[(t + 1) & 1]);
    }
    if (u >= 1) {
      const int t = u - 1;
      d1 = mk(h0buf[(t + 1) & 1], H_, h1buf[t & 1], H_, H_,
              WB_eWih1, eWih1, H_, WB_eWhh1, eWhh1, H_, 2048,
              eb1, nullptr, nullptr, C1, h1buf[(t + 1) & 1]);
    }
    launch(dim3(64, 8), d0, d1);
  }

  if (fast) {
    // decoder: fc fused into dl1 (PRED atomics); layer0 split into
    // GEMM (paired into the previous step's dl1 dispatch) + dec_cell.
    // Step t state: h0(t) in h0buf[(t+1)&1], h1(t) in h1buf[(t+1)&1].
    LayerDesc g0 = mk(h0buf[0], H_, h0buf[0], H_, 1024,
                      WB_dWhh0, dWhh0, H_, WB_dWhh0, dWhh0, H_, 1024,
                      db0, nullptr, nullptr, C0, nullptr);
    g0.gout = GBUF;
    launch(dim3(64, 4), g0, off_d);
    dec_cell_kernel<<<dim3(B_), dim3(256), 0, stream>>>(
        GBUF, db0, dWih0, nullptr, fcb, C0, h0buf[1]);

    for (int t = 0; t < TOUT; ++t) {
      LayerDesc dA = mk(h0buf[(t + 1) & 1], H_, h1buf[t & 1], H_, 1024,
                        WB_dWih1, dWih1, H_, WB_dWhh1, dWhh1, H_, 2048,
                        db1, nullptr, nullptr, C1, h1buf[(t + 1) & 1]);
      dA.fcW = fcW;
      dA.pred = PRED + (size_t)t * B_;
      LayerDesc dB = off_d;
      const bool more = (t + 1 < TOUT);
      if (more) {
        dB = mk(h0buf[(t + 1) & 1], H_, h0buf[(t + 1) & 1], H_, 1024,
                WB_dWhh0, dWhh0, H_, WB_dWhh0, dWhh0, H_, 1024,
                db0, nullptr, nullptr, C0, nullptr);
        dB.gout = GBUF;
      }
      launch(dim3(64, more ? 8 : 4), dA, dB);
      if (more)
        dec_cell_kernel<<<dim3(B_), dim3(256), 0, stream>>>(
            GBUF, db0, dWih0, PRED + (size_t)t * B_, fcb, C0, h0buf[t & 1]);
    }
    dec_out_kernel<<<dim3(TOUT), dim3(256), 0, stream>>>(PRED, fcb, out);
    return;
  }

  // -------- fallback: per-tick decoder with fp32 weights --------
  for (int t = 0; t < TOUT; ++t) {
    u16* h0i = h0buf[t & 1]; u16* h0o = h0buf[(t + 1) & 1];
    u16* h1i = h1buf[t & 1]; u16* h1o = h1buf[(t + 1) & 1];
    LayerDesc dl0 = mk(h0i, H_, h0i, H_, 1024,
                       WB_dWhh0, dWhh0, H_, WB_dWhh0, dWhh0, H_, 1024,
                       db0, dWih0, INP, C0, h0o);
    launch(dim3(64, 4), dl0, off_d);
    LayerDesc dl1 = mk(h0o, H_, h1i, H_, H_,
                       WB_dWih1, dWih1, H_, WB_dWhh1, dWhh1, H_, 2048,
                       db1, nullptr, nullptr, C1, h1o);
    launch(dim3(64, 4), dl1, off_d);
    fc_kernel<<<dim3(B_), dim3(256), 0, stream>>>(h1o, fcW, fcb, out, INP, t);
  }
}

// Round 11
// 5884.246 us; speedup vs baseline: 1.0621x; 1.0621x over previous
//
#include <hip/hip_runtime.h>

#define B_ 256
#define S_ 256
#define D_ 64
#define H_ 1024
#define G4 4096
#define TOUT 32

typedef unsigned short u16;
typedef __attribute__((ext_vector_type(8))) short short8;
typedef __attribute__((ext_vector_type(4))) float float4v;
typedef __attribute__((ext_vector_type(16))) float f32x16;

__device__ __forceinline__ float bf2f(u16 b) {
  return __uint_as_float(((unsigned int)b) << 16);
}
__device__ __forceinline__ u16 f2bf(float f) {
  unsigned int u = __float_as_uint(f);
  unsigned int r = (u + 0x7fffu + ((u >> 16) & 1u)) >> 16;
  return (u16)r;
}
__device__ __forceinline__ unsigned pack2(float a, float b) {
  return (unsigned)f2bf(a) | ((unsigned)f2bf(b) << 16);
}
__device__ __forceinline__ float sigm(float x) {
  return 1.f / (1.f + __expf(-x));
}
__device__ __forceinline__ float tanh_(float x) {
  float xc = fminf(fmaxf(x, -15.f), 15.f);
  float e = __expf(2.f * xc);
  return (e - 1.f) / (e + 1.f);
}

__global__ __launch_bounds__(256) void cvt_kernel(const float* __restrict__ src,
                                                  u16* __restrict__ dst, int n) {
  for (int i = blockIdx.x * blockDim.x + threadIdx.x; i < n;
       i += gridDim.x * blockDim.x)
    dst[i] = f2bf(src[i]);
}

__global__ __launch_bounds__(256) void zero_kernel(uint4* __restrict__ p, int n16) {
  for (int i = blockIdx.x * blockDim.x + threadIdx.x; i < n16;
       i += gridDim.x * blockDim.x)
    p[i] = make_uint4(0u, 0u, 0u, 0u);
}

struct LayerDesc {
  const u16* A0; int lda0;
  const u16* A1; int lda1; int klen0;
  const void* W0; int ldw0;
  const void* W1; int ldw1; int Ktot;
  const float* bias;   // fp32 [4096] original gate-blocked
  const float* wcol;   // fp32 [4096] dec input column, or null
  const float* inp;    // fp32 [B] scalar input, or null
  float* c;
  u16* h;
  int active;
  // extensions (all null for legacy uses):
  float* gout;         // if set: write raw gates [B][H][4] and skip the cell
  const float* fcW;    // with pred: fused fc weights (fp32 [H])
  float* pred;         // fused fc accumulator [B] (atomicAdd), pre-zeroed
};

// Paired LSTM step: blockIdx.y<4 -> dA (slot A), >=4 -> dB (slot B).
// Each 64x64 tile: gates = [A0|A1] @ [W0|W1]^T (+bias +inp*wcol in cell mode).
//
// v10 = v8 (K-split 32x32x16 core, cooperative reg-staged LDS dbuf, one
// barrier per 64-k chunk) + 2-DEEP GLOBAL PREFETCH via double-buffered
// STAGING REGISTERS (named even/odd sets, loop unrolled x2 -> no runtime-
// indexed register arrays):
//   loads for chunk kc+3 are issued at iter kc and consumed by stage() at
//   iter kc+2 -> ~2 iterations (~1900 cyc) of lead vs v8's 1 (~600-900).
//   This targets the vmcnt wait inside stage(), the per-chunk serial cost
//   that v8's LDS-count cut and v9's read-scheduling change both failed to
//   touch (their nulls exclude LDS throughput and LDS read latency).
//   8 global loads in flight instead of 4.  Everything else == v8.
template <bool WF32>
__global__ __launch_bounds__(256) void lstm_step_kernel(LayerDesc dA, LayerDesc dB)
{
  const bool second = (blockIdx.y >= 4);
  const LayerDesc d = second ? dB : dA;
  if (!d.active) return;

  // [0,18432) As[2][64][72], [18432,36864) Bs[2][64][72], [36864,54272) Gs[64][68]
  // epilogue scratch: 12 x 4096B regions at [0,49152) (staging dead; regions
  // 9-11 overlap Gs head -> extra barrier before the Gs scatter)
  __shared__ __align__(16) unsigned char SMEM[54272];
  u16 (*As)[64][72] = (u16(*)[64][72])(SMEM);
  u16 (*Bs)[64][72] = (u16(*)[64][72])(SMEM + 18432);
  float* Gs = (float*)(SMEM + 36864);   // row stride 68 floats
  float* scr = (float*)SMEM;            // 12 x 1024-float regions

  const int tid = threadIdx.x;
  const int m0 = (second ? (blockIdx.y - 4) : blockIdx.y) * 64;
  const int n0 = blockIdx.x * 64;
  const int ub = n0 >> 2;        // first hidden unit of this block
  const int r = tid >> 2;        // staging row 0..63
  const int q = tid & 3;         // staging 16-col group
  const int lane = tid & 63;
  const int wv = tid >> 6;
  const int l31 = lane & 31;

  const int klen0 = d.klen0;
  const u16* aw0 = d.A0 + (size_t)(m0 + r) * d.lda0;
  const u16* aw1 = d.A1 + (size_t)(m0 + r) * d.lda1;
  const int orow = (r & 3) * H_ + ub + (r >> 2);  // gate-col n0+r -> original W row
  const u16* bw0_h = (const u16*)d.W0 + (size_t)orow * d.ldw0;
  const u16* bw1_h = (const u16*)d.W1 + (size_t)orow * d.ldw1;
  const float* bw0_f = (const float*)d.W0 + (size_t)orow * d.ldw0;
  const float* bw1_f = (const float*)d.W1 + (size_t)orow * d.ldw1;

  // even/odd staging register sets (chunk kc -> set[kc&1])
  uint4 avE0, avE1, bvE0, bvE1;
  uint4 avO0, avO1, bvO0, bvO1;
  float4 bfE0, bfE1, bfE2, bfE3;
  float4 bfO0, bfO1, bfO2, bfO3;

  auto loadE = [&](int kc) {
    const int kg = kc * 64 + q * 16;
    const bool first = kg < klen0;
    const u16* pa = first ? (aw0 + kg) : (aw1 + (kg - klen0));
    avE0 = *(const uint4*)pa;
    avE1 = *(const uint4*)(pa + 8);
    if constexpr (WF32) {
      const float* pb = first ? (bw0_f + kg) : (bw1_f + (kg - klen0));
      bfE0 = *(const float4*)pb;
      bfE1 = *(const float4*)(pb + 4);
      bfE2 = *(const float4*)(pb + 8);
      bfE3 = *(const float4*)(pb + 12);
    } else {
      const u16* pb = first ? (bw0_h + kg) : (bw1_h + (kg - klen0));
      bvE0 = *(const uint4*)pb;
      bvE1 = *(const uint4*)(pb + 8);
    }
  };
  auto loadO = [&](int kc) {
    const int kg = kc * 64 + q * 16;
    const bool first = kg < klen0;
    const u16* pa = first ? (aw0 + kg) : (aw1 + (kg - klen0));
    avO0 = *(const uint4*)pa;
    avO1 = *(const uint4*)(pa + 8);
    if constexpr (WF32) {
      const float* pb = first ? (bw0_f + kg) : (bw1_f + (kg - klen0));
      bfO0 = *(const float4*)pb;
      bfO1 = *(const float4*)(pb + 4);
      bfO2 = *(const float4*)(pb + 8);
      bfO3 = *(const float4*)(pb + 12);
    } else {
      const u16* pb = first ? (bw0_h + kg) : (bw1_h + (kg - klen0));
      bvO0 = *(const uint4*)pb;
      bvO1 = *(const uint4*)(pb + 8);
    }
  };

  auto stageE = [&](int buf) {
    uint4 b0 = bvE0, b1 = bvE1;
    if constexpr (WF32) {
      b0 = make_uint4(pack2(bfE0.x, bfE0.y), pack2(bfE0.z, bfE0.w),
                      pack2(bfE1.x, bfE1.y), pack2(bfE1.z, bfE1.w));
      b1 = make_uint4(pack2(bfE2.x, bfE2.y), pack2(bfE2.z, bfE2.w),
                      pack2(bfE3.x, bfE3.y), pack2(bfE3.z, bfE3.w));
    }
    *(uint4*)&As[buf][r][q * 16]     = avE0;
    *(uint4*)&As[buf][r][q * 16 + 8] = avE1;
    *(uint4*)&Bs[buf][r][q * 16]     = b0;
    *(uint4*)&Bs[buf][r][q * 16 + 8] = b1;
  };
  auto stageO = [&](int buf) {
    uint4 b0 = bvO0, b1 = bvO1;
    if constexpr (WF32) {
      b0 = make_uint4(pack2(bfO0.x, bfO0.y), pack2(bfO0.z, bfO0.w),
                      pack2(bfO1.x, bfO1.y), pack2(bfO1.z, bfO1.w));
      b1 = make_uint4(pack2(bfO2.x, bfO2.y), pack2(bfO2.z, bfO2.w),
                      pack2(bfO3.x, bfO3.y), pack2(bfO3.z, bfO3.w));
    }
    *(uint4*)&As[buf][r][q * 16]     = avO0;
    *(uint4*)&As[buf][r][q * 16 + 8] = avO1;
    *(uint4*)&Bs[buf][r][q * 16]     = b0;
    *(uint4*)&Bs[buf][r][q * 16 + 8] = b1;
  };

  f32x16 acc00 = {}, acc01 = {}, acc10 = {}, acc11 = {};
  const int kb = wv * 16 + (lane >> 5) * 8;   // this wave's k-window + frag k
  const int nch = d.Ktot >> 6;

  auto mfma4 = [&](int cur) {   // v8's direct-LDS-read MFMA body, unchanged
    const short8 a0 = *(const short8*)&As[cur][l31][kb];
    const short8 a1 = *(const short8*)&As[cur][l31 + 32][kb];
    const short8 b0 = *(const short8*)&Bs[cur][l31][kb];
    const short8 b1 = *(const short8*)&Bs[cur][l31 + 32][kb];
    acc00 = __builtin_amdgcn_mfma_f32_32x32x16_bf16(a0, b0, acc00, 0, 0, 0);
    acc01 = __builtin_amdgcn_mfma_f32_32x32x16_bf16(a0, b1, acc01, 0, 0, 0);
    acc10 = __builtin_amdgcn_mfma_f32_32x32x16_bf16(a1, b0, acc10, 0, 0, 0);
    acc11 = __builtin_amdgcn_mfma_f32_32x32x16_bf16(a1, b1, acc11, 0, 0, 0);
  };

  // prologue: stage chunk 0; loads for chunks 1 (O) and 2 (E) in flight
  loadE(0);
  stageE(0);
  if (nch > 1) loadO(1);
  if (nch > 2) loadE(2);
  __syncthreads();  // buf0 ready

  for (int kc = 0; kc < nch; kc += 2) {
    // even iteration kc: compute buf0
    mfma4(0);
    if (kc + 1 < nch) {
      stageO(1);                          // chunk kc+1 (loaded 2 iters ago)
      if (kc + 3 < nch) loadO(kc + 3);    // 2-iteration lead
      __syncthreads();                    // publish buf1; fence buf1 readers
      // odd iteration kc+1: compute buf1
      mfma4(1);
      if (kc + 2 < nch) {
        stageE(0);                        // chunk kc+2 (loaded 2 iters ago)
        if (kc + 4 < nch) loadE(kc + 4);
        __syncthreads();                  // publish buf0
      }
    }
  }

  // ---- cross-wave K-reduction (v6/v8-proven): wave wv owns quadrant
  // (rows (wv>>1)*32, cols (wv&1)*32); acc order 00,01,10,11 = quadrants 0..3
  __syncthreads();   // all staging reads done; reuse As/Bs (+Gs head) as scratch

  auto store_frag = [&](const f32x16& A, int qd) {
    if (qd == wv) return;
    const int slot = (wv > qd) ? (wv - 1) : wv;
    float* rg = scr + (qd * 3 + slot) * 1024 + lane * 4;
#pragma unroll
    for (int j4 = 0; j4 < 4; ++j4)
      *(float4*)&rg[j4 * 256] = make_float4(A[j4 * 4 + 0], A[j4 * 4 + 1],
                                            A[j4 * 4 + 2], A[j4 * 4 + 3]);
  };
  store_frag(acc00, 0);
  store_frag(acc01, 1);
  store_frag(acc10, 2);
  store_frag(acc11, 3);
  __syncthreads();

  f32x16 fin = (wv == 0) ? acc00 : (wv == 1) ? acc01 : (wv == 2) ? acc10 : acc11;
#pragma unroll
  for (int s = 0; s < 3; ++s) {
    const float* rg = scr + (wv * 3 + s) * 1024 + lane * 4;
#pragma unroll
    for (int j4 = 0; j4 < 4; ++j4) {
      const float4 v = *(const float4*)&rg[j4 * 256];
      fin[j4 * 4 + 0] += v.x;
      fin[j4 * 4 + 1] += v.y;
      fin[j4 * 4 + 2] += v.z;
      fin[j4 * 4 + 3] += v.w;
    }
  }
  __syncthreads();   // regions 9-11 consumed before Gs scatter overwrites them

  // scatter owned quadrant to Gs; 32x32 C-layout: col=lane&31,
  // row=(reg&3)+8*(reg>>2)+4*(lane>>5)   [verified in v6/m101]
  {
    const int rbase = (wv >> 1) * 32 + (lane >> 5) * 4;
    const int col = (wv & 1) * 32 + l31;
#pragma unroll
    for (int j = 0; j < 16; ++j) {
      const int row = rbase + (j & 3) + 8 * (j >> 2);
      Gs[row * 68 + col] = fin[j];
    }
  }
  __syncthreads();

  if (d.gout != nullptr) {
    // raw-gates mode: gout[bg][J][g] = Gs[bl][u*4+g]; bias/pred applied later
#pragma unroll
    for (int it = 0; it < 4; ++it) {
      const int p = tid + it * 256;
      const int bl = p >> 4;
      const int u = p & 15;
      const int J = ub + u;
      const int bg = m0 + bl;
      const float4v g = *(const float4v*)&Gs[bl * 68 + u * 4];
      *(float4*)&d.gout[((size_t)bg * H_ + J) * 4] =
          make_float4(g[0], g[1], g[2], g[3]);
    }
    return;
  }

  // fused LSTM cell: 64 batches x 16 units; local col 4u+g = gate g of unit ub+u
#pragma unroll
  for (int it = 0; it < 4; ++it) {
    const int p = tid + it * 256;
    const int bl = p >> 4;
    const int u = p & 15;          // == lane & 15
    const int J = ub + u;
    const int bg = m0 + bl;
    const float4v g = *(const float4v*)&Gs[bl * 68 + u * 4];
    float pi = g[0] + d.bias[J];
    float pf = g[1] + d.bias[H_ + J];
    float pg = g[2] + d.bias[2 * H_ + J];
    float po = g[3] + d.bias[3 * H_ + J];
    if (d.inp != nullptr) {
      const float iv = d.inp[bg];
      pi += iv * d.wcol[J];
      pf += iv * d.wcol[H_ + J];
      pg += iv * d.wcol[2 * H_ + J];
      po += iv * d.wcol[3 * H_ + J];
    }
    const size_t idx = (size_t)bg * H_ + J;
    const float c = d.c[idx];
    const float cn = sigm(pf) * c + sigm(pi) * tanh_(pg);
    d.c[idx] = cn;
    const float hv = sigm(po) * tanh_(cn);
    d.h[idx] = f2bf(hv);
    if (d.pred != nullptr) {
      float s = hv * d.fcW[J];
      s += __shfl_xor(s, 1, 64);
      s += __shfl_xor(s, 2, 64);
      s += __shfl_xor(s, 4, 64);
      s += __shfl_xor(s, 8, 64);
      if (u == 0) atomicAdd(&d.pred[bg], s);   // 16-unit slice partial
    }
  }
}

// decoder layer0 cell: gates from GBUF (raw GEMM) + bias + iv*wcol, iv =
// pred_prev[b] + fcb (or 0 at t=0).  One block per batch, 4 units/thread.
__global__ __launch_bounds__(256) void dec_cell_kernel(
    const float* __restrict__ GBUF, const float* __restrict__ bias,
    const float* __restrict__ wcol, const float* __restrict__ pred_prev,
    const float* __restrict__ fcb, float* __restrict__ C,
    u16* __restrict__ hout)
{
  const int b = blockIdx.x;
  const int tid = threadIdx.x;
  const float iv = (pred_prev != nullptr) ? (pred_prev[b] + fcb[0]) : 0.f;
#pragma unroll
  for (int k = 0; k < 4; ++k) {
    const int J = tid + k * 256;
    const float4 g = *(const float4*)&GBUF[((size_t)b * H_ + J) * 4];
    const float pi = g.x + bias[J]          + iv * wcol[J];
    const float pf = g.y + bias[H_ + J]     + iv * wcol[H_ + J];
    const float pg = g.z + bias[2 * H_ + J] + iv * wcol[2 * H_ + J];
    const float po = g.w + bias[3 * H_ + J] + iv * wcol[3 * H_ + J];
    const size_t idx = (size_t)b * H_ + J;
    const float c0 = C[idx];
    const float cn = sigm(pf) * c0 + sigm(pi) * tanh_(pg);
    C[idx] = cn;
    hout[idx] = f2bf(sigm(po) * tanh_(cn));
  }
}

// out[b][t] = PRED[t][b] + fcb
__global__ __launch_bounds__(256) void dec_out_kernel(
    const float* __restrict__ PRED, const float* __restrict__ fcb,
    float* __restrict__ out)
{
  const int gid = blockIdx.x * 256 + threadIdx.x;
  const int b = gid >> 5;
  const int t = gid & 31;
  out[gid] = PRED[t * B_ + b] + fcb[0];
}

// pred[b] = fc_W . h1[b] + fc_b ; fp32 out + fp32 feedback (fallback path)
__global__ __launch_bounds__(256) void fc_kernel(
    const u16* __restrict__ h1, const float* __restrict__ fcW,
    const float* __restrict__ fcb, float* __restrict__ out,
    float* __restrict__ inp, int t)
{
  const int b = blockIdx.x;
  const int tid = threadIdx.x;
  const u16* hr = h1 + (size_t)b * H_ + tid * 4;
  const float* wr = fcW + tid * 4;
  float s = 0.f;
#pragma unroll
  for (int j = 0; j < 4; ++j) s += bf2f(hr[j]) * wr[j];
#pragma unroll
  for (int off = 32; off > 0; off >>= 1) s += __shfl_down(s, off, 64);
  __shared__ float red[4];
  if ((tid & 63) == 0) red[tid >> 6] = s;
  __syncthreads();
  if (tid == 0) {
    const float p = red[0] + red[1] + red[2] + red[3] + fcb[0];
    out[(size_t)b * TOUT + t] = p;
    inp[b] = p;
  }
}

extern "C" void kernel_launch(void* const* d_in, const int* in_sizes, int n_in,
                              void* d_out, int out_size, void* d_ws, size_t ws_size,
                              hipStream_t stream)
{
  const float* X     = (const float*)d_in[0];
  const float* eWih0 = (const float*)d_in[1];
  const float* eWhh0 = (const float*)d_in[2];
  const float* eb0   = (const float*)d_in[3];
  const float* eWih1 = (const float*)d_in[4];
  const float* eWhh1 = (const float*)d_in[5];
  const float* eb1   = (const float*)d_in[6];
  const float* dWih0 = (const float*)d_in[7];
  const float* dWhh0 = (const float*)d_in[8];
  const float* db0   = (const float*)d_in[9];
  const float* dWih1 = (const float*)d_in[10];
  const float* dWhh1 = (const float*)d_in[11];
  const float* db1   = (const float*)d_in[12];
  const float* fcW   = (const float*)d_in[13];
  const float* fcb   = (const float*)d_in[14];
  float* out = (float*)d_out;

  char* ws = (char*)d_ws;
  size_t off = 0;
  auto alloc = [&](size_t bytes) -> void* {
    void* p = ws + off;
    off += (bytes + 255) & ~(size_t)255;
    return p;
  };
  // state block first (zeroed every call)
  u16* h0buf[2], *h1buf[2];
  h0buf[0] = (u16*)alloc((size_t)B_ * H_ * 2);
  h0buf[1] = (u16*)alloc((size_t)B_ * H_ * 2);
  h1buf[0] = (u16*)alloc((size_t)B_ * H_ * 2);
  h1buf[1] = (u16*)alloc((size_t)B_ * H_ * 2);
  float* C0   = (float*)alloc((size_t)B_ * H_ * 4);
  float* C1   = (float*)alloc((size_t)B_ * H_ * 4);
  float* INP  = (float*)alloc(B_ * 4);
  float* PRED = (float*)alloc((size_t)TOUT * B_ * 4);  // zeroed (fc atomics)
  const size_t zbytes = off;
  u16* XB = (u16*)alloc((size_t)B_ * S_ * D_ * 2);
  // bf16 weight copies (fast path), original flat layouts
  u16* WB_eWih0 = (u16*)alloc((size_t)G4 * D_ * 2);
  u16* WB_eWhh0 = (u16*)alloc((size_t)G4 * H_ * 2);
  u16* WB_eWih1 = (u16*)alloc((size_t)G4 * H_ * 2);
  u16* WB_eWhh1 = (u16*)alloc((size_t)G4 * H_ * 2);
  u16* WB_dWhh0 = (u16*)alloc((size_t)G4 * H_ * 2);
  u16* WB_dWih1 = (u16*)alloc((size_t)G4 * H_ * 2);
  u16* WB_dWhh1 = (u16*)alloc((size_t)G4 * H_ * 2);
  float* GBUF   = (float*)alloc((size_t)B_ * H_ * 4 * 4);  // raw gates [B][H][4]
  const size_t need_full = off;
  const bool fast = (ws_size >= need_full);

  zero_kernel<<<dim3(256), dim3(256), 0, stream>>>((uint4*)ws, (int)(zbytes / 16));
  cvt_kernel<<<dim3(1024), dim3(256), 0, stream>>>(X, XB, B_ * S_ * D_);
  if (fast) {
    cvt_kernel<<<dim3(256), dim3(256), 0, stream>>>(eWih0, WB_eWih0, G4 * D_);
    cvt_kernel<<<dim3(1024), dim3(256), 0, stream>>>(eWhh0, WB_eWhh0, G4 * H_);
    cvt_kernel<<<dim3(1024), dim3(256), 0, stream>>>(eWih1, WB_eWih1, G4 * H_);
    cvt_kernel<<<dim3(1024), dim3(256), 0, stream>>>(eWhh1, WB_eWhh1, G4 * H_);
    cvt_kernel<<<dim3(1024), dim3(256), 0, stream>>>(dWhh0, WB_dWhh0, G4 * H_);
    cvt_kernel<<<dim3(1024), dim3(256), 0, stream>>>(dWih1, WB_dWih1, G4 * H_);
    cvt_kernel<<<dim3(1024), dim3(256), 0, stream>>>(dWhh1, WB_dWhh1, G4 * H_);
  }

  auto mk = [&](const u16* A0, int lda0, const u16* A1, int lda1, int klen0,
                const void* W0b, const void* W0f, int ldw0,
                const void* W1b, const void* W1f, int ldw1, int Ktot,
                const float* bias, const float* wcol, const float* inp,
                float* c, u16* h) {
    LayerDesc d;
    d.A0 = A0; d.lda0 = lda0; d.A1 = A1; d.lda1 = lda1; d.klen0 = klen0;
    d.W0 = fast ? W0b : W0f; d.ldw0 = ldw0;
    d.W1 = fast ? W1b : W1f; d.ldw1 = ldw1; d.Ktot = Ktot;
    d.bias = bias; d.wcol = wcol; d.inp = inp; d.c = c; d.h = h;
    d.active = 1;
    d.gout = nullptr; d.fcW = nullptr; d.pred = nullptr;
    return d;
  };
  LayerDesc off_d = {};
  off_d.active = 0;

  auto launch = [&](dim3 grid, const LayerDesc& a, const LayerDesc& b) {
    if (fast)
      lstm_step_kernel<false><<<grid, dim3(256), 0, stream>>>(a, b);
    else
      lstm_step_kernel<true><<<grid, dim3(256), 0, stream>>>(a, b);
  };

  // encoder, layer-pipelined: tick u runs L0(t=u) and L1(t=u-1) concurrently.
  // h ping-pong: L(t) reads hbuf[t&1], writes hbuf[(t+1)&1].
  for (int u = 0; u <= S_; ++u) {
    LayerDesc d0 = off_d, d1 = off_d;
    if (u < S_) {
      const int t = u;
      d0 = mk(XB + t * D_, S_ * D_, h0buf[t & 1], H_, D_,
              WB_eWih0, eWih0, D_, WB_eWhh0, eWhh0, H_, 1088,
              eb0, nullptr, nullptr, C0, h0buf[(t + 1) & 1]);
    }
    if (u >= 1) {
      const int t = u - 1;
      d1 = mk(h0buf[(t + 1) & 1], H_, h1buf[t & 1], H_, H_,
              WB_eWih1, eWih1, H_, WB_eWhh1, eWhh1, H_, 2048,
              eb1, nullptr, nullptr, C1, h1buf[(t + 1) & 1]);
    }
    launch(dim3(64, 8), d0, d1);
  }

  if (fast) {
    // decoder: fc fused into dl1 (PRED atomics); layer0 split into
    // GEMM (paired into the previous step's dl1 dispatch) + dec_cell.
    // Step t state: h0(t) in h0buf[(t+1)&1], h1(t) in h1buf[(t+1)&1].
    LayerDesc g0 = mk(h0buf[0], H_, h0buf[0], H_, 1024,
                      WB_dWhh0, dWhh0, H_, WB_dWhh0, dWhh0, H_, 1024,
                      db0, nullptr, nullptr, C0, nullptr);
    g0.gout = GBUF;
    launch(dim3(64, 4), g0, off_d);
    dec_cell_kernel<<<dim3(B_), dim3(256), 0, stream>>>(
        GBUF, db0, dWih0, nullptr, fcb, C0, h0buf[1]);

    for (int t = 0; t < TOUT; ++t) {
      LayerDesc dA = mk(h0buf[(t + 1) & 1], H_, h1buf[t & 1], H_, 1024,
                        WB_dWih1, dWih1, H_, WB_dWhh1, dWhh1, H_, 2048,
                        db1, nullptr, nullptr, C1, h1buf[(t + 1) & 1]);
      dA.fcW = fcW;
      dA.pred = PRED + (size_t)t * B_;
      LayerDesc dB = off_d;
      const bool more = (t + 1 < TOUT);
      if (more) {
        dB = mk(h0buf[(t + 1) & 1], H_, h0buf[(t + 1) & 1], H_, 1024,
                WB_dWhh0, dWhh0, H_, WB_dWhh0, dWhh0, H_, 1024,
                db0, nullptr, nullptr, C0, nullptr);
        dB.gout = GBUF;
      }
      launch(dim3(64, more ? 8 : 4), dA, dB);
      if (more)
        dec_cell_kernel<<<dim3(B_), dim3(256), 0, stream>>>(
            GBUF, db0, dWih0, PRED + (size_t)t * B_, fcb, C0, h0buf[t & 1]);
    }
    dec_out_kernel<<<dim3(TOUT), dim3(256), 0, stream>>>(PRED, fcb, out);
    return;
  }

  // -------- fallback: per-tick decoder with fp32 weights --------
  for (int t = 0; t < TOUT; ++t) {
    u16* h0i = h0buf[t & 1]; u16* h0o = h0buf[(t + 1) & 1];
    u16* h1i = h1buf[t & 1]; u16* h1o = h1buf[(t + 1) & 1];
    LayerDesc dl0 = mk(h0i, H_, h0i, H_, 1024,
                       WB_dWhh0, dWhh0, H_, WB_dWhh0, dWhh0, H_, 1024,
                       db0, dWih0, INP, C0, h0o);
    launch(dim3(64, 4), dl0, off_d);
    LayerDesc dl1 = mk(h0o, H_, h1i, H_, H_,
                       WB_dWih1, dWih1, H_, WB_dWhh1, dWhh1, H_, 2048,
                       db1, nullptr, nullptr, C1, h1o);
    launch(dim3(64, 4), dl1, off_d);
    fc_kernel<<<dim3(B_), dim3(256), 0, stream>>>(h1o, fcW, fcb, out, INP, t);
  }
}